// Round 5
// baseline (117.912 us; speedup 1.0000x reference)
//
#include <hip/hip_runtime.h>
#include <math.h>

typedef __bf16 b16x8 __attribute__((ext_vector_type(8)));
typedef float  f32x4 __attribute__((ext_vector_type(4)));

#define B_    8
#define CIN_  64
#define COUT_ 64
#define Hs    96
#define Ws    96
#define PLANE (Hs*Ws)        // 9216
#define IMG   (CIN_*PLANE)   // 589824
#define NP    (B_*PLANE)     // 73728
#define NBLK  (NP/64)        // 1152 blocks, 64 px each as a 4-row x 16-col tile

// LDS window for a 4x16 tile: rows h0-3..h0+6 (10), cols c0-3..c0+20 (24)
#define WR 10
#define WC 24
#define WPIX (WR*WC)         // 240
#define WBYTES (WPIX*128)    // 30720 B

__device__ __forceinline__ int swz(int bid) { return (bid & 7) * (NBLK / 8) + (bid >> 3); }

// Fused: blocks [0,288) transpose x -> channel-last bf16 xT;
//        blocks [288,432) repack weights into per-lane MFMA A-fragment order.
__global__ void prep_xpose(const float* __restrict__ x,
                           const float* __restrict__ weight, const float* __restrict__ w_off,
                           __bf16* __restrict__ xT,
                           __bf16* __restrict__ wAB, __bf16* __restrict__ wAO) {
    int bid = blockIdx.x;
    if (bid < 288) {
        int p = bid * 256 + threadIdx.x;
        int b = p / PLANE, r = p - b * PLANE;
        const float* src = x + b * IMG + r;
        __bf16 buf[64];
#pragma unroll
        for (int c = 0; c < 64; ++c) buf[c] = (__bf16)src[c * PLANE];
        b16x8* dst = (b16x8*)(xT + (size_t)p * 64);
#pragma unroll
        for (int j = 0; j < 8; ++j) dst[j] = ((const b16x8*)buf)[j];
    } else {
        int i = (bid - 288) * 256 + threadIdx.x;
        if (i < 36864) {
            int e = i & 7, lane = (i >> 3) & 63, mt = (i >> 9) & 3, ks = (i >> 11) & 1, k = i >> 12;
            int o = mt * 16 + (lane & 15);
            int c = ks * 32 + ((lane >> 4) << 3) + e;
            wAB[i] = (__bf16)weight[o * 576 + c * 9 + k];
        }
        if (i < 18432) {
            int e = i & 7, lane = (i >> 3) & 63, mt = (i >> 9) & 1, ks = (i >> 10) & 1, t = i >> 11;
            int ch = mt * 16 + (lane & 15);
            int c  = ks * 32 + ((lane >> 4) << 3) + e;
            wAO[i] = (ch < 27) ? (__bf16)w_off[ch * 576 + c * 9 + t] : (__bf16)(0.f);
        }
    }
}

// R5: 4x16 tile, NO K-split. R4 post-mortem: per-block fixed costs (halo
// staging, barriers, exchange epilogue, dispatch tail) dominate the ~40 us
// residual. 64 px/block amortizes the halo (240 lines/64px vs 192/32px:
// -37% chip-wide stage traffic), grid 2304->1152 at 4 blocks/CU => 1.125
// dispatch rounds (was 1.8). Full-K per wave makes om wave-private again:
// only ONE __syncthreads in the kernel (post-stage); no cross-half exchange.
// Inner loop = R0's proven full-K structure, sampling from the swizzled LDS
// window (R3's transaction fix).
__global__ __launch_bounds__(256, 4)
void deform_mfma(const __bf16* __restrict__ xT,
                 const __bf16* __restrict__ wAO,
                 const float* __restrict__ b_off,
                 const __bf16* __restrict__ wAB,
                 const float* __restrict__ bias,
                 float* __restrict__ out) {
    __shared__ __align__(16) unsigned char smemWin[WBYTES];   // 30720 B
    __shared__ float omL[4][27 * 16];                          // 6912 B, wave-private

    int tid  = threadIdx.x;
    int lane = tid & 63;
    int s    = __builtin_amdgcn_readfirstlane(tid >> 6);   // strip = row in tile
    int n    = lane & 15;    // pixel col within strip / MFMA col
    int q    = lane >> 4;    // octet: channels q*8..q*8+7 (ks0) / +32 (ks1)

    int t    = swz(blockIdx.x);
    int b    = t / 144;            // 144 tiles per image (24 row-quads x 6 col-tiles)
    int rem  = t - b * 144;
    int rq   = rem / 6;
    int ct   = rem - rq * 6;
    int h0   = rq * 4;             // tile top row
    int c0   = ct * 16;            // tile left col
    int hrow = h0 + s;             // this strip's row
    int w    = c0 + n;             // this lane's col

    const __bf16* xTimg = xT + (size_t)b * PLANE * 64;
    const __bf16* xTb   = xTimg + q * 8;   // fallback gather base (ks0 octet)

    const b16x8* wAOv = (const b16x8*)wAO;
    const b16x8* wABv = (const b16x8*)wAB;
    int boff = q * 16;   // ks0 byte offset within a pixel line; ks1 at boff+64

#define LDSRD(sl, off) (*(const b16x8*)(smemWin + (sl) * 128 + ((off) ^ (((sl) & 7) << 4))))

    // ---------------- Stage window: 240 px * 128 B, coalesced ---------------
    // 1920 chunks over 256 threads (7.5 each). Swizzled write: byte chunk
    // j*16 ^ (slot&7)<<4 spreads phase reads across 8 bank groups.
#pragma unroll
    for (int r2 = 0; r2 < 8; ++r2) {
        int idx = tid + r2 * 256;
        if (r2 < 7 || tid < (WPIX * 8 - 1792)) {
            int pix = idx >> 3, j = idx & 7;
            int yw = pix / WC, xw = pix - yw * WC;
            int ys = min(max(h0 - 3 + yw, 0), Hs - 1);
            int xs = min(max(c0 - 3 + xw, 0), Ws - 1);
            b16x8 v = *(const b16x8*)(xTimg + ((ys * Ws + xs) * 64) + j * 8);
            *(b16x8*)(smemWin + pix * 128 + ((j * 16) ^ ((pix & 7) << 4))) = v;
        }
    }
    __syncthreads();

    // ---------------- Phase A: offset conv via MFMA (full K) ----------------
    // Taps sample (hrow-1+ky, w-1+kx): rows h0-1..h0+5, cols c0-1..c0+16 --
    // always inside the window (rows 2..9, cols 2..19 of it).
    f32x4 accA0 = {0.f, 0.f, 0.f, 0.f};
    f32x4 accA1 = {0.f, 0.f, 0.f, 0.f};
    const b16x8 ZER = {};

#pragma unroll 3
    for (int tt = 0; tt < 9; ++tt) {
        int ky = tt / 3, kx = tt - ky * 3;
        int yy = hrow - 1 + ky, xx = w - 1 + kx;
        bool mk = (yy >= 0 && yy < Hs && xx >= 0 && xx < Ws);   // zero-pad conv
        int sl = (s + 2 + ky) * WC + (n + 2 + kx);
        b16x8 bf0 = LDSRD(sl, boff);
        b16x8 bf1 = LDSRD(sl, boff + 64);
        bf0 = mk ? bf0 : ZER;
        bf1 = mk ? bf1 : ZER;
        b16x8 af0 = wAOv[((tt * 2 + 0) * 2 + 0) * 64 + lane];
        b16x8 af1 = wAOv[((tt * 2 + 0) * 2 + 1) * 64 + lane];
        b16x8 af2 = wAOv[((tt * 2 + 1) * 2 + 0) * 64 + lane];
        b16x8 af3 = wAOv[((tt * 2 + 1) * 2 + 1) * 64 + lane];
        accA0 = __builtin_amdgcn_mfma_f32_16x16x32_bf16(af0, bf0, accA0, 0, 0, 0);
        accA1 = __builtin_amdgcn_mfma_f32_16x16x32_bf16(af1, bf0, accA1, 0, 0, 0);
        accA0 = __builtin_amdgcn_mfma_f32_16x16x32_bf16(af2, bf1, accA0, 0, 0, 0);
        accA1 = __builtin_amdgcn_mfma_f32_16x16x32_bf16(af3, bf1, accA1, 0, 0, 0);
    }
    // om is wave-private: no barrier needed (same wave writes then reads).
    float* omW = &omL[s][0];
#pragma unroll
    for (int rg = 0; rg < 4; ++rg) { int ch = q * 4 + rg;      omW[ch * 16 + n] = accA0[rg] + b_off[ch]; }
#pragma unroll
    for (int rg = 0; rg < 4; ++rg) { int ch = 16 + q * 4 + rg; if (ch < 27) omW[ch * 16 + n] = accA1[rg] + b_off[ch]; }

    // ---------------- Phase B: sampling (from LDS) + main conv --------------
    f32x4 acc0 = {0.f, 0.f, 0.f, 0.f};
    f32x4 acc1 = {0.f, 0.f, 0.f, 0.f};
    f32x4 acc2 = {0.f, 0.f, 0.f, 0.f};
    f32x4 acc3 = {0.f, 0.f, 0.f, 0.f};

#pragma unroll 3
    for (int k = 0; k < 9; ++k) {
        float dy = omW[(2 * k) * 16 + n];
        float dx = omW[(2 * k + 1) * 16 + n];
        float mo = omW[(18 + k) * 16 + n];

        float m  = 1.f / (1.f + __expf(-mo));
        int ky = k / 3, kx = k - ky * 3;
        float ysf = (float)(hrow - 1 + ky) + dy;
        float xsf = (float)(w    - 1 + kx) + dx;
        float y0f = floorf(ysf), x0f = floorf(xsf);
        float ly = ysf - y0f, lx = xsf - x0f;
        float hy = 1.f - ly, hx = 1.f - lx;
        int y0 = (int)y0f, x0 = (int)x0f, y1 = y0 + 1, x1 = x0 + 1;
        bool vy0 = (y0 >= 0) && (y0 < Hs), vy1 = (y1 >= 0) && (y1 < Hs);
        bool vx0 = (x0 >= 0) && (x0 < Ws), vx1 = (x1 >= 0) && (x1 < Ws);
        float W00 = (vy0 && vx0) ? m * hy * hx : 0.f;
        float W01 = (vy0 && vx1) ? m * hy * lx : 0.f;
        float W10 = (vy1 && vx0) ? m * ly * hx : 0.f;
        float W11 = (vy1 && vx1) ? m * ly * lx : 0.f;

        // window membership on UNCLAMPED coords (slot content is clamped data;
        // zero-weight kills out-of-image corners exactly as before)
        bool inw = (y0 >= h0 - 3) && (y1 <= h0 + 6) && (x0 >= c0 - 3) && (x1 <= c0 + 20);

        b16x8 e00, e01, e10, e11, o00, o01, o10, o11;
        if (inw) {
            int sl = (y0 - (h0 - 3)) * WC + (x0 - (c0 - 3));
            e00 = LDSRD(sl, boff);           o00 = LDSRD(sl, boff + 64);
            e01 = LDSRD(sl + 1, boff);       o01 = LDSRD(sl + 1, boff + 64);
            e10 = LDSRD(sl + WC, boff);      o10 = LDSRD(sl + WC, boff + 64);
            e11 = LDSRD(sl + WC + 1, boff);  o11 = LDSRD(sl + WC + 1, boff + 64);
        } else {   // exact fallback: clamped global gather (rare/never)
            int y0c = min(max(y0, 0), Hs - 1), y1c = min(max(y1, 0), Hs - 1);
            int x0c = min(max(x0, 0), Ws - 1), x1c = min(max(x1, 0), Ws - 1);
            const b16x8* P00 = (const b16x8*)(xTb + (y0c * Ws + x0c) * 64);
            const b16x8* P01 = (const b16x8*)(xTb + (y0c * Ws + x1c) * 64);
            const b16x8* P10 = (const b16x8*)(xTb + (y1c * Ws + x0c) * 64);
            const b16x8* P11 = (const b16x8*)(xTb + (y1c * Ws + x1c) * 64);
            e00 = P00[0]; o00 = P00[4];
            e01 = P01[0]; o01 = P01[4];
            e10 = P10[0]; o10 = P10[4];
            e11 = P11[0]; o11 = P11[4];
        }

        b16x8 a0 = wABv[(k * 8 + 0) * 64 + lane];
        b16x8 a1 = wABv[(k * 8 + 1) * 64 + lane];
        b16x8 a2 = wABv[(k * 8 + 2) * 64 + lane];
        b16x8 a3 = wABv[(k * 8 + 3) * 64 + lane];

        b16x8 fe;
#pragma unroll
        for (int j = 0; j < 8; ++j)
            fe[j] = (__bf16)((float)e00[j] * W00 + (float)e01[j] * W01 +
                             (float)e10[j] * W10 + (float)e11[j] * W11);
        acc0 = __builtin_amdgcn_mfma_f32_16x16x32_bf16(a0, fe, acc0, 0, 0, 0);
        acc1 = __builtin_amdgcn_mfma_f32_16x16x32_bf16(a1, fe, acc1, 0, 0, 0);
        acc2 = __builtin_amdgcn_mfma_f32_16x16x32_bf16(a2, fe, acc2, 0, 0, 0);
        acc3 = __builtin_amdgcn_mfma_f32_16x16x32_bf16(a3, fe, acc3, 0, 0, 0);

        b16x8 a4 = wABv[(k * 8 + 4) * 64 + lane];
        b16x8 a5 = wABv[(k * 8 + 5) * 64 + lane];
        b16x8 a6 = wABv[(k * 8 + 6) * 64 + lane];
        b16x8 a7 = wABv[(k * 8 + 7) * 64 + lane];

        b16x8 fo;
#pragma unroll
        for (int j = 0; j < 8; ++j)
            fo[j] = (__bf16)((float)o00[j] * W00 + (float)o01[j] * W01 +
                             (float)o10[j] * W10 + (float)o11[j] * W11);
        acc0 = __builtin_amdgcn_mfma_f32_16x16x32_bf16(a4, fo, acc0, 0, 0, 0);
        acc1 = __builtin_amdgcn_mfma_f32_16x16x32_bf16(a5, fo, acc1, 0, 0, 0);
        acc2 = __builtin_amdgcn_mfma_f32_16x16x32_bf16(a6, fo, acc2, 0, 0, 0);
        acc3 = __builtin_amdgcn_mfma_f32_16x16x32_bf16(a7, fo, acc3, 0, 0, 0);
    }
#undef LDSRD

    // ---------------- Epilogue: direct store (no exchange) ------------------
    int ob = b * (COUT_ * PLANE) + hrow * Ws + w;
    f32x4 bs0 = *(const f32x4*)&bias[q * 4];
    f32x4 bs1 = *(const f32x4*)&bias[16 + q * 4];
    f32x4 bs2 = *(const f32x4*)&bias[32 + q * 4];
    f32x4 bs3 = *(const f32x4*)&bias[48 + q * 4];
#pragma unroll
    for (int rg = 0; rg < 4; ++rg) { int o =      q * 4 + rg; out[ob + o * PLANE] = acc0[rg] + bs0[rg]; }
#pragma unroll
    for (int rg = 0; rg < 4; ++rg) { int o = 16 + q * 4 + rg; out[ob + o * PLANE] = acc1[rg] + bs1[rg]; }
#pragma unroll
    for (int rg = 0; rg < 4; ++rg) { int o = 32 + q * 4 + rg; out[ob + o * PLANE] = acc2[rg] + bs2[rg]; }
#pragma unroll
    for (int rg = 0; rg < 4; ++rg) { int o = 48 + q * 4 + rg; out[ob + o * PLANE] = acc3[rg] + bs3[rg]; }
}

extern "C" void kernel_launch(void* const* d_in, const int* in_sizes, int n_in,
                              void* d_out, int out_size, void* d_ws, size_t ws_size,
                              hipStream_t stream) {
    const float* x      = (const float*)d_in[0];
    const float* w_off  = (const float*)d_in[1];
    const float* b_off  = (const float*)d_in[2];
    const float* weight = (const float*)d_in[3];
    const float* bias   = (const float*)d_in[4];
    float* out = (float*)d_out;

    char* ws = (char*)d_ws;
    __bf16* wAB = (__bf16*)ws;               //  73728 B
    __bf16* wAO = (__bf16*)(ws + 73728);     //  36864 B
    __bf16* xT  = (__bf16*)(ws + 131072);    // 9437184 B (bf16 channel-last)

    prep_xpose<<<432, 256, 0, stream>>>(x, weight, w_off, xT, wAB, wAO);
    deform_mfma<<<NBLK, 256, 0, stream>>>(xT, wAO, b_off, wAB, bias, out);
}

// Round 6
// 113.825 us; speedup vs baseline: 1.0359x; 1.0359x over previous
//
#include <hip/hip_runtime.h>
#include <math.h>

typedef __bf16 b16x8 __attribute__((ext_vector_type(8)));
typedef float  f32x4 __attribute__((ext_vector_type(4)));

#define B_    8
#define CIN_  64
#define COUT_ 64
#define Hs    96
#define Ws    96
#define PLANE (Hs*Ws)        // 9216
#define IMG   (CIN_*PLANE)   // 589824
#define NP    (B_*PLANE)     // 73728
#define NBLK  (NP/64)        // 1152 blocks, 64 px each as a 4-row x 16-col tile

// LDS window for a 4x16 tile with +/-1 offset margin:
// rows h0-2..h0+6 (9), cols c0-2..c0+18 (21). Offsets are ~N(0,0.24) so
// |d|>1 is ~3e-5; the exact global fallback handles those lanes.
#define WR 9
#define WC 21
#define WPIX (WR*WC)         // 189
#define WSTG 192             // padded to 6 full 256-thread stage rounds
#define WBYTES (WSTG*128)    // 24576 B

__device__ __forceinline__ int swz(int bid) { return (bid & 7) * (NBLK / 8) + (bid >> 3); }

// Fused: blocks [0,288) transpose x -> channel-last bf16 xT;
//        blocks [288,432) repack weights into per-lane MFMA A-fragment order.
__global__ void prep_xpose(const float* __restrict__ x,
                           const float* __restrict__ weight, const float* __restrict__ w_off,
                           __bf16* __restrict__ xT,
                           __bf16* __restrict__ wAB, __bf16* __restrict__ wAO) {
    int bid = blockIdx.x;
    if (bid < 288) {
        int p = bid * 256 + threadIdx.x;
        int b = p / PLANE, r = p - b * PLANE;
        const float* src = x + b * IMG + r;
        __bf16 buf[64];
#pragma unroll
        for (int c = 0; c < 64; ++c) buf[c] = (__bf16)src[c * PLANE];
        b16x8* dst = (b16x8*)(xT + (size_t)p * 64);
#pragma unroll
        for (int j = 0; j < 8; ++j) dst[j] = ((const b16x8*)buf)[j];
    } else {
        int i = (bid - 288) * 256 + threadIdx.x;
        if (i < 36864) {
            int e = i & 7, lane = (i >> 3) & 63, mt = (i >> 9) & 3, ks = (i >> 11) & 1, k = i >> 12;
            int o = mt * 16 + (lane & 15);
            int c = ks * 32 + ((lane >> 4) << 3) + e;
            wAB[i] = (__bf16)weight[o * 576 + c * 9 + k];
        }
        if (i < 18432) {
            int e = i & 7, lane = (i >> 3) & 63, mt = (i >> 9) & 1, ks = (i >> 10) & 1, t = i >> 11;
            int ch = mt * 16 + (lane & 15);
            int c  = ks * 32 + ((lane >> 4) << 3) + e;
            wAO[i] = (ch < 27) ? (__bf16)w_off[ch * 576 + c * 9 + t] : (__bf16)(0.f);
        }
    }
}

// R6: LDS window (R3's transaction fix) + R0's explicit 1-deep software
// pipeline in phase B. R3/R4/R5 post-mortem: deform pinned at ~43-46 us
// across three tilings/occupancies => the cost is the straight-line per-tap
// dependent chain (om LDS read -> addr -> 8 LDS reads -> 130-op combine ->
// MFMA, ~550 cyc x 9, mostly stall). R0 hid 3-4x larger GLOBAL latency with
// a half-tap pipeline at 70 us; here the same pipeline covers ~120-cyc LDS
// latency with the combine+MFMA of the previous half-tap. unroll 1 keeps the
// body small (I-cache). Window shrunk to the +/-1-offset margin (9x21):
// -20% stage traffic; exact global fallback for |d|>1 lanes (P ~ 3e-5).
__global__ __launch_bounds__(256, 4)
void deform_mfma(const __bf16* __restrict__ xT,
                 const __bf16* __restrict__ wAO,
                 const float* __restrict__ b_off,
                 const __bf16* __restrict__ wAB,
                 const float* __restrict__ bias,
                 float* __restrict__ out) {
    __shared__ __align__(16) unsigned char smemWin[WBYTES];   // 24576 B
    __shared__ float omL[4][27 * 16];                          // 6912 B, wave-private

    int tid  = threadIdx.x;
    int lane = tid & 63;
    int s    = __builtin_amdgcn_readfirstlane(tid >> 6);   // strip = row in tile
    int n    = lane & 15;    // pixel col within strip / MFMA col
    int q    = lane >> 4;    // octet: channels q*8..q*8+7 (ks0) / +32 (ks1)

    int t    = swz(blockIdx.x);
    int b    = t / 144;            // 144 tiles per image (24 row-quads x 6 col-tiles)
    int rem  = t - b * 144;
    int rq   = rem / 6;
    int ct   = rem - rq * 6;
    int h0   = rq * 4;             // tile top row
    int c0   = ct * 16;            // tile left col
    int hrow = h0 + s;             // this strip's row
    int w    = c0 + n;             // this lane's col

    const __bf16* xTimg = xT + (size_t)b * PLANE * 64;
    const __bf16* xTb   = xTimg + q * 8;   // fallback gather base (ks0 octet)

    const b16x8* wAOv = (const b16x8*)wAO;
    const b16x8* wABv = (const b16x8*)wAB;
    int boff = q * 16;   // ks0 byte offset within a pixel line; ks1 at boff+64

#define LDSRD(sl_, off_) (*(const b16x8*)(smemWin + (sl_) * 128 + ((off_) ^ (((sl_) & 7) << 4))))

    // ---------------- Stage window: 189 px (pad 192) * 128 B, coalesced -----
    // 1536 chunks = exactly 6 per thread. Swizzled write: byte chunk
    // j*16 ^ (pix&7)<<4 spreads phase reads across 8 bank groups.
#pragma unroll
    for (int r2 = 0; r2 < 6; ++r2) {
        int idx = tid + r2 * 256;
        int pix = idx >> 3, j = idx & 7;
        int yw = pix / WC, xw = pix - yw * WC;          // pad rows clamp below
        int ys = min(max(h0 - 2 + yw, 0), Hs - 1);
        int xs = min(max(c0 - 2 + xw, 0), Ws - 1);
        b16x8 v = *(const b16x8*)(xTimg + ((ys * Ws + xs) * 64) + j * 8);
        *(b16x8*)(smemWin + pix * 128 + ((j * 16) ^ ((pix & 7) << 4))) = v;
    }
    __syncthreads();

    // ---------------- Phase A: offset conv via MFMA (full K) ----------------
    // Taps sample (hrow-1+ky, w-1+kx): window rows 1..6, cols 1..18.
    f32x4 accA0 = {0.f, 0.f, 0.f, 0.f};
    f32x4 accA1 = {0.f, 0.f, 0.f, 0.f};
    const b16x8 ZER = {};

#pragma unroll 3
    for (int tt = 0; tt < 9; ++tt) {
        int ky = tt / 3, kx = tt - ky * 3;
        int yy = hrow - 1 + ky, xx = w - 1 + kx;
        bool mk = (yy >= 0 && yy < Hs && xx >= 0 && xx < Ws);   // zero-pad conv
        int slA = (s + 1 + ky) * WC + (n + 1 + kx);
        b16x8 bf0 = LDSRD(slA, boff);
        b16x8 bf1 = LDSRD(slA, boff + 64);
        bf0 = mk ? bf0 : ZER;
        bf1 = mk ? bf1 : ZER;
        b16x8 af0 = wAOv[((tt * 2 + 0) * 2 + 0) * 64 + lane];
        b16x8 af1 = wAOv[((tt * 2 + 0) * 2 + 1) * 64 + lane];
        b16x8 af2 = wAOv[((tt * 2 + 1) * 2 + 0) * 64 + lane];
        b16x8 af3 = wAOv[((tt * 2 + 1) * 2 + 1) * 64 + lane];
        accA0 = __builtin_amdgcn_mfma_f32_16x16x32_bf16(af0, bf0, accA0, 0, 0, 0);
        accA1 = __builtin_amdgcn_mfma_f32_16x16x32_bf16(af1, bf0, accA1, 0, 0, 0);
        accA0 = __builtin_amdgcn_mfma_f32_16x16x32_bf16(af2, bf1, accA0, 0, 0, 0);
        accA1 = __builtin_amdgcn_mfma_f32_16x16x32_bf16(af3, bf1, accA1, 0, 0, 0);
    }
    // om is wave-private: no barrier needed (same wave writes then reads).
    float* omW = &omL[s][0];
#pragma unroll
    for (int rg = 0; rg < 4; ++rg) { int ch = q * 4 + rg;      omW[ch * 16 + n] = accA0[rg] + b_off[ch]; }
#pragma unroll
    for (int rg = 0; rg < 4; ++rg) { int ch = 16 + q * 4 + rg; if (ch < 27) omW[ch * 16 + n] = accA1[rg] + b_off[ch]; }

    // ---------------- Phase B: pipelined sampling + main conv ---------------
    f32x4 acc0 = {0.f, 0.f, 0.f, 0.f};
    f32x4 acc1 = {0.f, 0.f, 0.f, 0.f};
    f32x4 acc2 = {0.f, 0.f, 0.f, 0.f};
    f32x4 acc3 = {0.f, 0.f, 0.f, 0.f};

    float W00, W01, W10, W11;   // current tap bilinear weights (mask folded)
    int   sl, y0r, x0r;         // current tap window slot / raw corner coords
    bool  inw;                  // current tap fully-in-window predicate
    b16x8 e00, e01, e10, e11;   // current tap ks0 octets (prefetched)

#define CALC_FROM(dy, dx, mo, kk) do {                                            \
        float m  = 1.f / (1.f + __expf(-(mo)));                                   \
        int ky = (kk) / 3, kx = (kk) - ky * 3;                                    \
        float ysf = (float)(hrow - 1 + ky) + (dy);                                \
        float xsf = (float)(w    - 1 + kx) + (dx);                                \
        float y0f = floorf(ysf), x0f = floorf(xsf);                               \
        float ly = ysf - y0f, lx = xsf - x0f;                                     \
        float hy = 1.f - ly, hx = 1.f - lx;                                       \
        y0r = (int)y0f; x0r = (int)x0f;                                           \
        int y1 = y0r + 1, x1 = x0r + 1;                                           \
        bool vy0 = (y0r >= 0) && (y0r < Hs), vy1 = (y1 >= 0) && (y1 < Hs);        \
        bool vx0 = (x0r >= 0) && (x0r < Ws), vx1 = (x1 >= 0) && (x1 < Ws);        \
        W00 = (vy0 && vx0) ? m * hy * hx : 0.f;                                   \
        W01 = (vy0 && vx1) ? m * hy * lx : 0.f;                                   \
        W10 = (vy1 && vx0) ? m * ly * hx : 0.f;                                   \
        W11 = (vy1 && vx1) ? m * ly * lx : 0.f;                                   \
        inw = (y0r >= h0 - 2) && (y1 <= h0 + 6) && (x0r >= c0 - 2) && (x1 <= c0 + 18); \
        sl  = (y0r - (h0 - 2)) * WC + (x0r - (c0 - 2));                           \
    } while (0)

    // Load 4 corner octets at element-offset ELO (0=ks0, 32=ks1) for the
    // current tap: LDS fast path, exact clamped-global fallback (execz-skipped).
#define LOAD4(d0, d1, d2, d3, OFF, ELO) do {                                      \
        if (inw) {                                                                \
            d0 = LDSRD(sl, OFF);          d1 = LDSRD(sl + 1, OFF);                \
            d2 = LDSRD(sl + WC, OFF);     d3 = LDSRD(sl + WC + 1, OFF);           \
        } else {                                                                  \
            int y0c = min(max(y0r, 0), Hs - 1), y1c = min(max(y0r + 1, 0), Hs - 1); \
            int x0c = min(max(x0r, 0), Ws - 1), x1c = min(max(x0r + 1, 0), Ws - 1); \
            d0 = *(const b16x8*)(xTb + (y0c * Ws + x0c) * 64 + (ELO));            \
            d1 = *(const b16x8*)(xTb + (y0c * Ws + x1c) * 64 + (ELO));            \
            d2 = *(const b16x8*)(xTb + (y1c * Ws + x0c) * 64 + (ELO));            \
            d3 = *(const b16x8*)(xTb + (y1c * Ws + x1c) * 64 + (ELO));            \
        }                                                                         \
    } while (0)

    {   // prologue: tap 0 addresses + ks0 octets
        float dy0 = omW[0 * 16 + n], dx0 = omW[1 * 16 + n], mo0 = omW[18 * 16 + n];
        CALC_FROM(dy0, dx0, mo0, 0);
        LOAD4(e00, e01, e10, e11, boff, 0);
    }

#pragma unroll 1
    for (int k = 0; k < 9; ++k) {
        b16x8 a0 = wABv[(k * 8 + 0) * 64 + lane];
        b16x8 a1 = wABv[(k * 8 + 1) * 64 + lane];
        b16x8 a2 = wABv[(k * 8 + 2) * 64 + lane];
        b16x8 a3 = wABv[(k * 8 + 3) * 64 + lane];

        // tap k's ks1 octets (current sl/inw), issued before the combine
        b16x8 o00, o01, o10, o11;
        LOAD4(o00, o01, o10, o11, boff + 64, 32);

        // prefetch tap k+1's om triple (latency hidden behind combine+MFMA)
        int kn = (k < 8) ? (k + 1) : 8;
        float dyN = omW[(2 * kn) * 16 + n];
        float dxN = omW[(2 * kn + 1) * 16 + n];
        float moN = omW[(18 + kn) * 16 + n];

        float V00 = W00, V01 = W01, V10 = W10, V11 = W11;   // save for fo

        b16x8 fe;
#pragma unroll
        for (int j = 0; j < 8; ++j)
            fe[j] = (__bf16)((float)e00[j] * W00 + (float)e01[j] * W01 +
                             (float)e10[j] * W10 + (float)e11[j] * W11);
        acc0 = __builtin_amdgcn_mfma_f32_16x16x32_bf16(a0, fe, acc0, 0, 0, 0);
        acc1 = __builtin_amdgcn_mfma_f32_16x16x32_bf16(a1, fe, acc1, 0, 0, 0);
        acc2 = __builtin_amdgcn_mfma_f32_16x16x32_bf16(a2, fe, acc2, 0, 0, 0);
        acc3 = __builtin_amdgcn_mfma_f32_16x16x32_bf16(a3, fe, acc3, 0, 0, 0);

        b16x8 a4 = wABv[(k * 8 + 4) * 64 + lane];
        b16x8 a5 = wABv[(k * 8 + 5) * 64 + lane];
        b16x8 a6 = wABv[(k * 8 + 6) * 64 + lane];
        b16x8 a7 = wABv[(k * 8 + 7) * 64 + lane];

        if (k < 8) {   // CALC(k+1) + its ks0 octets; covered by fo combine+MFMAs
            CALC_FROM(dyN, dxN, moN, k + 1);
            LOAD4(e00, e01, e10, e11, boff, 0);
        }

        b16x8 fo;
#pragma unroll
        for (int j = 0; j < 8; ++j)
            fo[j] = (__bf16)((float)o00[j] * V00 + (float)o01[j] * V01 +
                             (float)o10[j] * V10 + (float)o11[j] * V11);
        acc0 = __builtin_amdgcn_mfma_f32_16x16x32_bf16(a4, fo, acc0, 0, 0, 0);
        acc1 = __builtin_amdgcn_mfma_f32_16x16x32_bf16(a5, fo, acc1, 0, 0, 0);
        acc2 = __builtin_amdgcn_mfma_f32_16x16x32_bf16(a6, fo, acc2, 0, 0, 0);
        acc3 = __builtin_amdgcn_mfma_f32_16x16x32_bf16(a7, fo, acc3, 0, 0, 0);
    }
#undef LOAD4
#undef CALC_FROM
#undef LDSRD

    // ---------------- Epilogue: direct store (no exchange) ------------------
    int ob = b * (COUT_ * PLANE) + hrow * Ws + w;
    f32x4 bs0 = *(const f32x4*)&bias[q * 4];
    f32x4 bs1 = *(const f32x4*)&bias[16 + q * 4];
    f32x4 bs2 = *(const f32x4*)&bias[32 + q * 4];
    f32x4 bs3 = *(const f32x4*)&bias[48 + q * 4];
#pragma unroll
    for (int rg = 0; rg < 4; ++rg) { int o =      q * 4 + rg; out[ob + o * PLANE] = acc0[rg] + bs0[rg]; }
#pragma unroll
    for (int rg = 0; rg < 4; ++rg) { int o = 16 + q * 4 + rg; out[ob + o * PLANE] = acc1[rg] + bs1[rg]; }
#pragma unroll
    for (int rg = 0; rg < 4; ++rg) { int o = 32 + q * 4 + rg; out[ob + o * PLANE] = acc2[rg] + bs2[rg]; }
#pragma unroll
    for (int rg = 0; rg < 4; ++rg) { int o = 48 + q * 4 + rg; out[ob + o * PLANE] = acc3[rg] + bs3[rg]; }
}

extern "C" void kernel_launch(void* const* d_in, const int* in_sizes, int n_in,
                              void* d_out, int out_size, void* d_ws, size_t ws_size,
                              hipStream_t stream) {
    const float* x      = (const float*)d_in[0];
    const float* w_off  = (const float*)d_in[1];
    const float* b_off  = (const float*)d_in[2];
    const float* weight = (const float*)d_in[3];
    const float* bias   = (const float*)d_in[4];
    float* out = (float*)d_out;

    char* ws = (char*)d_ws;
    __bf16* wAB = (__bf16*)ws;               //  73728 B
    __bf16* wAO = (__bf16*)(ws + 73728);     //  36864 B
    __bf16* xT  = (__bf16*)(ws + 131072);    // 9437184 B (bf16 channel-last)

    prep_xpose<<<432, 256, 0, stream>>>(x, weight, w_off, xT, wAB, wAO);
    deform_mfma<<<NBLK, 256, 0, stream>>>(xT, wAO, b_off, wAB, bias, out);
}

// Round 8
// 110.756 us; speedup vs baseline: 1.0646x; 1.0277x over previous
//
#include <hip/hip_runtime.h>
#include <math.h>

typedef __bf16 b16x8 __attribute__((ext_vector_type(8)));
typedef float  f32x4 __attribute__((ext_vector_type(4)));
typedef float  f32x2 __attribute__((ext_vector_type(2)));

#define B_    8
#define CIN_  64
#define COUT_ 64
#define Hs    96
#define Ws    96
#define PLANE (Hs*Ws)        // 9216
#define IMG   (CIN_*PLANE)   // 589824
#define NP    (B_*PLANE)     // 73728
#define NBLK  (NP/64)        // 1152 blocks, 64 px each as a 4-row x 16-col tile

// LDS window for a 4x16 tile with +/-1 offset margin:
// rows h0-2..h0+6 (9), cols c0-2..c0+18 (21). Offsets are ~N(0,0.24) so
// |d|>1 is ~3e-5; the exact global fallback handles those lanes.
#define WR 9
#define WC 21
#define WPIX (WR*WC)         // 189
#define WSTG 192             // padded to 6 full 256-thread stage rounds
#define WBYTES (WSTG*128)    // 24576 B

__device__ __forceinline__ int swz(int bid) { return (bid & 7) * (NBLK / 8) + (bid >> 3); }

// Fused: blocks [0,144) transpose x -> channel-last bf16 xT (2 px/thread,
// float2 coalesced reads); blocks [144,288) repack weights into per-lane
// MFMA A-fragment order.
__global__ void prep_xpose(const float* __restrict__ x,
                           const float* __restrict__ weight, const float* __restrict__ w_off,
                           __bf16* __restrict__ xT,
                           __bf16* __restrict__ wAB, __bf16* __restrict__ wAO) {
    int bid = blockIdx.x;
    if (bid < 144) {
        // 2 pixels per thread: lane reads float2 (2 adjacent px, same channel)
        // -> 512 B/wave-instr coalesced; halves load-instr count vs 1 px/thread.
        int p0 = (bid * 256 + threadIdx.x) * 2;
        int b = p0 / PLANE, r0 = p0 - b * PLANE;   // p0 even, PLANE even -> same image
        const float* src = x + b * IMG + r0;
        __bf16 buf0[64], buf1[64];
#pragma unroll
        for (int c = 0; c < 64; ++c) {
            f32x2 v = *(const f32x2*)(src + c * PLANE);
            buf0[c] = (__bf16)v[0];
            buf1[c] = (__bf16)v[1];
        }
        b16x8* dst = (b16x8*)(xT + (size_t)p0 * 64);
#pragma unroll
        for (int j = 0; j < 8; ++j) dst[j] = ((const b16x8*)buf0)[j];
#pragma unroll
        for (int j = 0; j < 8; ++j) dst[8 + j] = ((const b16x8*)buf1)[j];
    } else {
        int i = (bid - 144) * 256 + threadIdx.x;
        if (i < 36864) {
            int e = i & 7, lane = (i >> 3) & 63, mt = (i >> 9) & 3, ks = (i >> 11) & 1, k = i >> 12;
            int o = mt * 16 + (lane & 15);
            int c = ks * 32 + ((lane >> 4) << 3) + e;
            wAB[i] = (__bf16)weight[o * 576 + c * 9 + k];
        }
        if (i < 18432) {
            int e = i & 7, lane = (i >> 3) & 63, mt = (i >> 9) & 1, ks = (i >> 10) & 1, t = i >> 11;
            int ch = mt * 16 + (lane & 15);
            int c  = ks * 32 + ((lane >> 4) << 3) + e;
            wAO[i] = (ch < 27) ? (__bf16)w_off[ch * 576 + c * 9 + t] : (__bf16)(0.f);
        }
    }
}

// R8 (= R7 resubmit; R7 bench was an infra failure, not a kernel failure).
// R6 structure + occupancy unlock. Post-window regime (R3+) is
// latency-bound and occupancy-sensitive (R4@20w=115.1 < R5@16w=117.9; R6
// pipeline=113.8). R6's LDS = 31488 B already fits 5 blocks/CU (157.4 KB),
// but launch_bounds(256,4) let the allocator run to 128 VGPR -> residency
// VGPR-capped at 4. (256,5) caps at 102 VGPR: 5 blocks/CU = 20 waves (62%),
// and grid 1152 <= capacity 1280 -> SINGLE dispatch round, no tail.
// a4-a7 weight loads moved after the next-tap prefetch to trim peak live
// range (help the allocator hit 102 without spill).
__global__ __launch_bounds__(256, 5)
void deform_mfma(const __bf16* __restrict__ xT,
                 const __bf16* __restrict__ wAO,
                 const float* __restrict__ b_off,
                 const __bf16* __restrict__ wAB,
                 const float* __restrict__ bias,
                 float* __restrict__ out) {
    __shared__ __align__(16) unsigned char smemWin[WBYTES];   // 24576 B
    __shared__ float omL[4][27 * 16];                          // 6912 B, wave-private

    int tid  = threadIdx.x;
    int lane = tid & 63;
    int s    = __builtin_amdgcn_readfirstlane(tid >> 6);   // strip = row in tile
    int n    = lane & 15;    // pixel col within strip / MFMA col
    int q    = lane >> 4;    // octet: channels q*8..q*8+7 (ks0) / +32 (ks1)

    int t    = swz(blockIdx.x);
    int b    = t / 144;            // 144 tiles per image (24 row-quads x 6 col-tiles)
    int rem  = t - b * 144;
    int rq   = rem / 6;
    int ct   = rem - rq * 6;
    int h0   = rq * 4;             // tile top row
    int c0   = ct * 16;            // tile left col
    int hrow = h0 + s;             // this strip's row
    int w    = c0 + n;             // this lane's col

    const __bf16* xTimg = xT + (size_t)b * PLANE * 64;
    const __bf16* xTb   = xTimg + q * 8;   // fallback gather base (ks0 octet)

    const b16x8* wAOv = (const b16x8*)wAO;
    const b16x8* wABv = (const b16x8*)wAB;
    int boff = q * 16;   // ks0 byte offset within a pixel line; ks1 at boff+64

#define LDSRD(sl_, off_) (*(const b16x8*)(smemWin + (sl_) * 128 + ((off_) ^ (((sl_) & 7) << 4))))

    // ---------------- Stage window: 189 px (pad 192) * 128 B, coalesced -----
    // 1536 chunks = exactly 6 per thread. Swizzled write: byte chunk
    // j*16 ^ (pix&7)<<4 spreads phase reads across 8 bank groups.
#pragma unroll
    for (int r2 = 0; r2 < 6; ++r2) {
        int idx = tid + r2 * 256;
        int pix = idx >> 3, j = idx & 7;
        int yw = pix / WC, xw = pix - yw * WC;          // pad rows clamp below
        int ys = min(max(h0 - 2 + yw, 0), Hs - 1);
        int xs = min(max(c0 - 2 + xw, 0), Ws - 1);
        b16x8 v = *(const b16x8*)(xTimg + ((ys * Ws + xs) * 64) + j * 8);
        *(b16x8*)(smemWin + pix * 128 + ((j * 16) ^ ((pix & 7) << 4))) = v;
    }
    __syncthreads();

    // ---------------- Phase A: offset conv via MFMA (full K) ----------------
    // Taps sample (hrow-1+ky, w-1+kx): window rows 1..6, cols 1..18.
    f32x4 accA0 = {0.f, 0.f, 0.f, 0.f};
    f32x4 accA1 = {0.f, 0.f, 0.f, 0.f};
    const b16x8 ZER = {};

#pragma unroll 3
    for (int tt = 0; tt < 9; ++tt) {
        int ky = tt / 3, kx = tt - ky * 3;
        int yy = hrow - 1 + ky, xx = w - 1 + kx;
        bool mk = (yy >= 0 && yy < Hs && xx >= 0 && xx < Ws);   // zero-pad conv
        int slA = (s + 1 + ky) * WC + (n + 1 + kx);
        b16x8 bf0 = LDSRD(slA, boff);
        b16x8 bf1 = LDSRD(slA, boff + 64);
        bf0 = mk ? bf0 : ZER;
        bf1 = mk ? bf1 : ZER;
        b16x8 af0 = wAOv[((tt * 2 + 0) * 2 + 0) * 64 + lane];
        b16x8 af1 = wAOv[((tt * 2 + 0) * 2 + 1) * 64 + lane];
        b16x8 af2 = wAOv[((tt * 2 + 1) * 2 + 0) * 64 + lane];
        b16x8 af3 = wAOv[((tt * 2 + 1) * 2 + 1) * 64 + lane];
        accA0 = __builtin_amdgcn_mfma_f32_16x16x32_bf16(af0, bf0, accA0, 0, 0, 0);
        accA1 = __builtin_amdgcn_mfma_f32_16x16x32_bf16(af1, bf0, accA1, 0, 0, 0);
        accA0 = __builtin_amdgcn_mfma_f32_16x16x32_bf16(af2, bf1, accA0, 0, 0, 0);
        accA1 = __builtin_amdgcn_mfma_f32_16x16x32_bf16(af3, bf1, accA1, 0, 0, 0);
    }
    // om is wave-private: no barrier needed (same wave writes then reads).
    float* omW = &omL[s][0];
#pragma unroll
    for (int rg = 0; rg < 4; ++rg) { int ch = q * 4 + rg;      omW[ch * 16 + n] = accA0[rg] + b_off[ch]; }
#pragma unroll
    for (int rg = 0; rg < 4; ++rg) { int ch = 16 + q * 4 + rg; if (ch < 27) omW[ch * 16 + n] = accA1[rg] + b_off[ch]; }

    // ---------------- Phase B: pipelined sampling + main conv ---------------
    f32x4 acc0 = {0.f, 0.f, 0.f, 0.f};
    f32x4 acc1 = {0.f, 0.f, 0.f, 0.f};
    f32x4 acc2 = {0.f, 0.f, 0.f, 0.f};
    f32x4 acc3 = {0.f, 0.f, 0.f, 0.f};

    float W00, W01, W10, W11;   // current tap bilinear weights (mask folded)
    int   sl, y0r, x0r;         // current tap window slot / raw corner coords
    bool  inw;                  // current tap fully-in-window predicate
    b16x8 e00, e01, e10, e11;   // current tap ks0 octets (prefetched)

#define CALC_FROM(dy, dx, mo, kk) do {                                            \
        float m  = 1.f / (1.f + __expf(-(mo)));                                   \
        int ky = (kk) / 3, kx = (kk) - ky * 3;                                    \
        float ysf = (float)(hrow - 1 + ky) + (dy);                                \
        float xsf = (float)(w    - 1 + kx) + (dx);                                \
        float y0f = floorf(ysf), x0f = floorf(xsf);                               \
        float ly = ysf - y0f, lx = xsf - x0f;                                     \
        float hy = 1.f - ly, hx = 1.f - lx;                                       \
        y0r = (int)y0f; x0r = (int)x0f;                                           \
        int y1 = y0r + 1, x1 = x0r + 1;                                           \
        bool vy0 = (y0r >= 0) && (y0r < Hs), vy1 = (y1 >= 0) && (y1 < Hs);        \
        bool vx0 = (x0r >= 0) && (x0r < Ws), vx1 = (x1 >= 0) && (x1 < Ws);        \
        W00 = (vy0 && vx0) ? m * hy * hx : 0.f;                                   \
        W01 = (vy0 && vx1) ? m * hy * lx : 0.f;                                   \
        W10 = (vy1 && vx0) ? m * ly * hx : 0.f;                                   \
        W11 = (vy1 && vx1) ? m * ly * lx : 0.f;                                   \
        inw = (y0r >= h0 - 2) && (y1 <= h0 + 6) && (x0r >= c0 - 2) && (x1 <= c0 + 18); \
        sl  = (y0r - (h0 - 2)) * WC + (x0r - (c0 - 2));                           \
    } while (0)

    // Load 4 corner octets at element-offset ELO (0=ks0, 32=ks1) for the
    // current tap: LDS fast path, exact clamped-global fallback (execz-skipped).
#define LOAD4(d0, d1, d2, d3, OFF, ELO) do {                                      \
        if (inw) {                                                                \
            d0 = LDSRD(sl, OFF);          d1 = LDSRD(sl + 1, OFF);                \
            d2 = LDSRD(sl + WC, OFF);     d3 = LDSRD(sl + WC + 1, OFF);           \
        } else {                                                                  \
            int y0c = min(max(y0r, 0), Hs - 1), y1c = min(max(y0r + 1, 0), Hs - 1); \
            int x0c = min(max(x0r, 0), Ws - 1), x1c = min(max(x0r + 1, 0), Ws - 1); \
            d0 = *(const b16x8*)(xTb + (y0c * Ws + x0c) * 64 + (ELO));            \
            d1 = *(const b16x8*)(xTb + (y0c * Ws + x1c) * 64 + (ELO));            \
            d2 = *(const b16x8*)(xTb + (y1c * Ws + x0c) * 64 + (ELO));            \
            d3 = *(const b16x8*)(xTb + (y1c * Ws + x1c) * 64 + (ELO));            \
        }                                                                         \
    } while (0)

    {   // prologue: tap 0 addresses + ks0 octets
        float dy0 = omW[0 * 16 + n], dx0 = omW[1 * 16 + n], mo0 = omW[18 * 16 + n];
        CALC_FROM(dy0, dx0, mo0, 0);
        LOAD4(e00, e01, e10, e11, boff, 0);
    }

#pragma unroll 1
    for (int k = 0; k < 9; ++k) {
        b16x8 a0 = wABv[(k * 8 + 0) * 64 + lane];
        b16x8 a1 = wABv[(k * 8 + 1) * 64 + lane];
        b16x8 a2 = wABv[(k * 8 + 2) * 64 + lane];
        b16x8 a3 = wABv[(k * 8 + 3) * 64 + lane];

        // tap k's ks1 octets (current sl/inw), issued before the combine
        b16x8 o00, o01, o10, o11;
        LOAD4(o00, o01, o10, o11, boff + 64, 32);

        // prefetch tap k+1's om triple (latency hidden behind combine+MFMA)
        int kn = (k < 8) ? (k + 1) : 8;
        float dyN = omW[(2 * kn) * 16 + n];
        float dxN = omW[(2 * kn + 1) * 16 + n];
        float moN = omW[(18 + kn) * 16 + n];

        float V00 = W00, V01 = W01, V10 = W10, V11 = W11;   // save for fo

        b16x8 fe;
#pragma unroll
        for (int j = 0; j < 8; ++j)
            fe[j] = (__bf16)((float)e00[j] * W00 + (float)e01[j] * W01 +
                             (float)e10[j] * W10 + (float)e11[j] * W11);
        acc0 = __builtin_amdgcn_mfma_f32_16x16x32_bf16(a0, fe, acc0, 0, 0, 0);
        acc1 = __builtin_amdgcn_mfma_f32_16x16x32_bf16(a1, fe, acc1, 0, 0, 0);
        acc2 = __builtin_amdgcn_mfma_f32_16x16x32_bf16(a2, fe, acc2, 0, 0, 0);
        acc3 = __builtin_amdgcn_mfma_f32_16x16x32_bf16(a3, fe, acc3, 0, 0, 0);

        if (k < 8) {   // CALC(k+1) + its ks0 octets; covered by fo combine+MFMAs
            CALC_FROM(dyN, dxN, moN, k + 1);
            LOAD4(e00, e01, e10, e11, boff, 0);
        }

        // a4-a7 loaded late (short live range -> lower peak VGPR pressure)
        b16x8 a4 = wABv[(k * 8 + 4) * 64 + lane];
        b16x8 a5 = wABv[(k * 8 + 5) * 64 + lane];
        b16x8 a6 = wABv[(k * 8 + 6) * 64 + lane];
        b16x8 a7 = wABv[(k * 8 + 7) * 64 + lane];

        b16x8 fo;
#pragma unroll
        for (int j = 0; j < 8; ++j)
            fo[j] = (__bf16)((float)o00[j] * V00 + (float)o01[j] * V01 +
                             (float)o10[j] * V10 + (float)o11[j] * V11);
        acc0 = __builtin_amdgcn_mfma_f32_16x16x32_bf16(a4, fo, acc0, 0, 0, 0);
        acc1 = __builtin_amdgcn_mfma_f32_16x16x32_bf16(a5, fo, acc1, 0, 0, 0);
        acc2 = __builtin_amdgcn_mfma_f32_16x16x32_bf16(a6, fo, acc2, 0, 0, 0);
        acc3 = __builtin_amdgcn_mfma_f32_16x16x32_bf16(a7, fo, acc3, 0, 0, 0);
    }
#undef LOAD4
#undef CALC_FROM
#undef LDSRD

    // ---------------- Epilogue: direct store (no exchange) ------------------
    int ob = b * (COUT_ * PLANE) + hrow * Ws + w;
    f32x4 bs0 = *(const f32x4*)&bias[q * 4];
    f32x4 bs1 = *(const f32x4*)&bias[16 + q * 4];
    f32x4 bs2 = *(const f32x4*)&bias[32 + q * 4];
    f32x4 bs3 = *(const f32x4*)&bias[48 + q * 4];
#pragma unroll
    for (int rg = 0; rg < 4; ++rg) { int o =      q * 4 + rg; out[ob + o * PLANE] = acc0[rg] + bs0[rg]; }
#pragma unroll
    for (int rg = 0; rg < 4; ++rg) { int o = 16 + q * 4 + rg; out[ob + o * PLANE] = acc1[rg] + bs1[rg]; }
#pragma unroll
    for (int rg = 0; rg < 4; ++rg) { int o = 32 + q * 4 + rg; out[ob + o * PLANE] = acc2[rg] + bs2[rg]; }
#pragma unroll
    for (int rg = 0; rg < 4; ++rg) { int o = 48 + q * 4 + rg; out[ob + o * PLANE] = acc3[rg] + bs3[rg]; }
}

extern "C" void kernel_launch(void* const* d_in, const int* in_sizes, int n_in,
                              void* d_out, int out_size, void* d_ws, size_t ws_size,
                              hipStream_t stream) {
    const float* x      = (const float*)d_in[0];
    const float* w_off  = (const float*)d_in[1];
    const float* b_off  = (const float*)d_in[2];
    const float* weight = (const float*)d_in[3];
    const float* bias   = (const float*)d_in[4];
    float* out = (float*)d_out;

    char* ws = (char*)d_ws;
    __bf16* wAB = (__bf16*)ws;               //  73728 B
    __bf16* wAO = (__bf16*)(ws + 73728);     //  36864 B
    __bf16* xT  = (__bf16*)(ws + 131072);    // 9437184 B (bf16 channel-last)

    prep_xpose<<<288, 256, 0, stream>>>(x, weight, w_off, xT, wAB, wAO);
    deform_mfma<<<NBLK, 256, 0, stream>>>(xT, wAO, b_off, wAB, bias, out);
}